// Round 1
// baseline (1851.065 us; speedup 1.0000x reference)
//
#include <hip/hip_runtime.h>
#include <stdint.h>

typedef unsigned short u16;
typedef short bf16x8 __attribute__((ext_vector_type(8)));
typedef float f32x4 __attribute__((ext_vector_type(4)));

#define MFMA16(a, b, c) __builtin_amdgcn_mfma_f32_16x16x32_bf16((a), (b), (c), 0, 0, 0)

#define GLOAD_LDS16(gp, lp)                                                        \
  __builtin_amdgcn_global_load_lds((const __attribute__((address_space(1))) void*)(gp), \
                                   (__attribute__((address_space(3))) void*)(lp), 16, 0, 0)

__device__ __forceinline__ u16 f2bf(float x) {
  union { float f; uint32_t u; } v; v.f = x;
  uint32_t r = (v.u + 0x7FFFu + ((v.u >> 16) & 1u)) >> 16;
  return (u16)r;
}

// ---------------- transpose + fp32->bf16 convert: in[R][C] f32 -> out[C][R] bf16
__global__ __launch_bounds__(256) void transpose_bf16(const float* __restrict__ in,
                                                      u16* __restrict__ out, int R, int C) {
  __shared__ float tile[32][33];
  int nCt = C >> 5;
  int bid = blockIdx.x;
  int r0 = (bid / nCt) << 5, c0 = (bid % nCt) << 5;
  int t = threadIdx.x;
  int r = t >> 3, cc = (t & 7) << 2;
  float4 v = *reinterpret_cast<const float4*>(in + (size_t)(r0 + r) * C + c0 + cc);
  tile[r][cc] = v.x; tile[r][cc + 1] = v.y; tile[r][cc + 2] = v.z; tile[r][cc + 3] = v.w;
  __syncthreads();
  int c = t >> 3, rr = (t & 7) << 2;
  ushort4 u;
  u.x = f2bf(tile[rr][c]);     u.y = f2bf(tile[rr + 1][c]);
  u.z = f2bf(tile[rr + 2][c]); u.w = f2bf(tile[rr + 3][c]);
  *reinterpret_cast<ushort4*>(out + (size_t)(c0 + c) * R + r0 + rr) = u;
}

// ---------------- LayerNorm (H=4096) -> bf16
__global__ __launch_bounds__(256) void ln_bf16(const float* __restrict__ in,
                                               const float* __restrict__ w,
                                               const float* __restrict__ bia,
                                               u16* __restrict__ out) {
  int row = blockIdx.x, t = threadIdx.x;
  const float* x = in + (size_t)row * 4096;
  float4 v[4];
  float s = 0.f, sq = 0.f;
#pragma unroll
  for (int i = 0; i < 4; i++) {
    v[i] = *reinterpret_cast<const float4*>(x + i * 1024 + t * 4);
    s  += v[i].x + v[i].y + v[i].z + v[i].w;
    sq += v[i].x * v[i].x + v[i].y * v[i].y + v[i].z * v[i].z + v[i].w * v[i].w;
  }
#pragma unroll
  for (int off = 32; off > 0; off >>= 1) { s += __shfl_down(s, off); sq += __shfl_down(sq, off); }
  __shared__ float red[8];
  int wid = t >> 6, lane = t & 63;
  if (lane == 0) { red[wid] = s; red[4 + wid] = sq; }
  __syncthreads();
  if (t == 0) {
    float st = red[0] + red[1] + red[2] + red[3];
    float sqt = red[4] + red[5] + red[6] + red[7];
    float mu = st * (1.f / 4096.f);
    float var = sqt * (1.f / 4096.f) - mu * mu;
    red[0] = mu; red[1] = rsqrtf(var + 1e-5f);
  }
  __syncthreads();
  float mu = red[0], rs = red[1];
#pragma unroll
  for (int i = 0; i < 4; i++) {
    float4 wv = *reinterpret_cast<const float4*>(w + i * 1024 + t * 4);
    float4 bv = *reinterpret_cast<const float4*>(bia + i * 1024 + t * 4);
    ushort4 u;
    u.x = f2bf((v[i].x - mu) * rs * wv.x + bv.x);
    u.y = f2bf((v[i].y - mu) * rs * wv.y + bv.y);
    u.z = f2bf((v[i].z - mu) * rs * wv.z + bv.z);
    u.w = f2bf((v[i].w - mu) * rs * wv.w + bv.w);
    *reinterpret_cast<ushort4*>(out + (size_t)row * 4096 + i * 1024 + t * 4) = u;
  }
}

// ---------------- m97-style GEMM: C[M][N] = A[M][K] * Bt[N][K]^T, bf16 in, 128x128 tile, BK=32
// EPI==1: QKV epilogue (n<8192 -> qk buffer ldc=8192 bf16; n>=8192 -> vT[b][h][d][s] bf16)
// EPI==2: f32 row-major out (ldc=N)
template <int EPI>
__global__ __launch_bounds__(256) void gemm_bt(const u16* __restrict__ A, const u16* __restrict__ Bt,
                                               void* __restrict__ Cout, u16* __restrict__ vT,
                                               int M, int N, int K, int nbn) {
  __shared__ u16 As[128 * 32];
  __shared__ u16 Bs[128 * 32];
  int bid = blockIdx.x;
  int m0 = (bid / nbn) << 7, n0 = (bid % nbn) << 7;
  int t = threadIdx.x;
  int wid = t >> 6, lane = t & 63;
  int wr = (wid >> 1) << 6, wc = (wid & 1) << 6;
  int llo = lane & 15, lhi = lane >> 4;
  f32x4 acc[4][4] = {};
  for (int k0 = 0; k0 < K; k0 += 32) {
    __syncthreads();
#pragma unroll
    for (int i = 0; i < 2; i++) {
      int G = (i << 8) + t;
      int row = G >> 2, g = (G & 3) << 3;  // element offset in k
      GLOAD_LDS16(A + (size_t)(m0 + row) * K + k0 + g, &As[G << 3]);
      GLOAD_LDS16(Bt + (size_t)(n0 + row) * K + k0 + g, &Bs[G << 3]);
    }
    __syncthreads();
    bf16x8 af[4], bfr[4];
#pragma unroll
    for (int mf = 0; mf < 4; mf++)
      af[mf] = *reinterpret_cast<const bf16x8*>(&As[((wr + (mf << 4) + llo) << 5) + (lhi << 3)]);
#pragma unroll
    for (int nf = 0; nf < 4; nf++)
      bfr[nf] = *reinterpret_cast<const bf16x8*>(&Bs[((wc + (nf << 4) + llo) << 5) + (lhi << 3)]);
#pragma unroll
    for (int mf = 0; mf < 4; mf++)
#pragma unroll
      for (int nf = 0; nf < 4; nf++)
        acc[mf][nf] = MFMA16(af[mf], bfr[nf], acc[mf][nf]);
  }
  // epilogue
  if (EPI == 2) {
    float* C = (float*)Cout;
#pragma unroll
    for (int mf = 0; mf < 4; mf++)
#pragma unroll
      for (int nf = 0; nf < 4; nf++) {
        int m = m0 + wr + (mf << 4) + (lhi << 2);
        int n = n0 + wc + (nf << 4) + llo;
#pragma unroll
        for (int r = 0; r < 4; r++) C[(size_t)(m + r) * N + n] = acc[mf][nf][r];
      }
  } else {
    if (n0 < 8192) {
      u16* qkb = (u16*)Cout;
#pragma unroll
      for (int mf = 0; mf < 4; mf++)
#pragma unroll
        for (int nf = 0; nf < 4; nf++) {
          int m = m0 + wr + (mf << 4) + (lhi << 2);
          int n = n0 + wc + (nf << 4) + llo;
#pragma unroll
          for (int r = 0; r < 4; r++) qkb[(size_t)(m + r) * 8192 + n] = f2bf(acc[mf][nf][r]);
        }
    } else {
#pragma unroll
      for (int mf = 0; mf < 4; mf++)
#pragma unroll
        for (int nf = 0; nf < 4; nf++) {
          int m = m0 + wr + (mf << 4) + (lhi << 2);
          int n_ = n0 + wc + (nf << 4) + llo - 8192;
          int h = n_ >> 8, d = n_ & 255;
          int b = m >> 8, s = m & 255;
          ushort4 u;
          u.x = f2bf(acc[mf][nf][0]); u.y = f2bf(acc[mf][nf][1]);
          u.z = f2bf(acc[mf][nf][2]); u.w = f2bf(acc[mf][nf][3]);
          *reinterpret_cast<ushort4*>(vT + ((size_t)((b << 4) + h) * 256 + d) * 256 + s) = u;
        }
    }
  }
}

// ---------------- attention: block = (b, h, 64 q-rows); 4 waves, each 16 q-rows
__global__ __launch_bounds__(256) void attn_kernel(const u16* __restrict__ qk,
                                                   const u16* __restrict__ vT,
                                                   const int* __restrict__ mask,
                                                   u16* __restrict__ ctx) {
  __shared__ u16 KV[64 * 256];   // 32 KiB: K tiles, then Vt tiles (swizzled rows)
  __shared__ u16 P[64 * 256];    // 32 KiB: probs [64 q][256 key] (swizzled rows)
  __shared__ float maskf[256];
  int bx = blockIdx.x;
  int qt = bx & 3, h = (bx >> 2) & 15, b = bx >> 6;
  int t = threadIdx.x, wid = t >> 6, lane = t & 63, llo = lane & 15, lhi = lane >> 4;
  maskf[t] = mask[(b << 8) + t] ? -1e30f : 0.0f;
  // Q fragments: row = b*256 + qt*64 + wid*16 + llo; k-chunks d = lhi*8 + c*32
  bf16x8 qf[8];
  {
    const u16* qrow = qk + (size_t)((b << 8) + (qt << 6) + (wid << 4) + llo) * 8192 + (h << 8);
#pragma unroll
    for (int c = 0; c < 8; c++)
      qf[c] = *reinterpret_cast<const bf16x8*>(qrow + (lhi << 3) + (c << 5));
  }
  f32x4 sacc[16] = {};
#pragma unroll 1
  for (int kt = 0; kt < 4; kt++) {
    __syncthreads();
    // stage K tile [64 key][256 d], row = 512B = 32 granules, src pre-swizzled g^(key&7)
#pragma unroll
    for (int i = 0; i < 8; i++) {
      int G = (i << 8) + t;
      int key = G >> 5, g = G & 31;
      int gs = g ^ (key & 7);
      const u16* src = qk + (size_t)((b << 8) + (kt << 6) + key) * 8192 + 4096 + (h << 8) + (gs << 3);
      GLOAD_LDS16(src, (char*)KV + (G << 4));
    }
    __syncthreads();
#pragma unroll
    for (int nf = 0; nf < 4; nf++) {
      int kl = (nf << 4) + llo;
      const char* kb = (const char*)KV + (kl << 9);
      int sw = (kl & 7) << 4;
#pragma unroll
      for (int c = 0; c < 8; c++) {
        bf16x8 kf = *reinterpret_cast<const bf16x8*>(kb + (((lhi << 4) + (c << 6)) ^ sw));
        sacc[kt * 4 + nf] = MFMA16(qf[c], kf, sacc[kt * 4 + nf]);
      }
    }
  }
  // softmax over 256 keys; score row q = wid*16 + lhi*4 + r; col key = kt*64+nf*16+llo
  float madd[16];
#pragma unroll
  for (int f = 0; f < 16; f++)
    madd[f] = maskf[((f >> 2) << 6) + ((f & 3) << 4) + llo];
  float mx[4] = {-3e38f, -3e38f, -3e38f, -3e38f};
#pragma unroll
  for (int f = 0; f < 16; f++)
#pragma unroll
    for (int r = 0; r < 4; r++) {
      float sv = sacc[f][r] * 0.0625f + madd[f];
      sacc[f][r] = sv;
      mx[r] = fmaxf(mx[r], sv);
    }
#pragma unroll
  for (int r = 0; r < 4; r++)
#pragma unroll
    for (int d = 1; d < 16; d <<= 1) mx[r] = fmaxf(mx[r], __shfl_xor(mx[r], d));
  float sum[4] = {0.f, 0.f, 0.f, 0.f};
#pragma unroll
  for (int f = 0; f < 16; f++)
#pragma unroll
    for (int r = 0; r < 4; r++) {
      float p = __expf(sacc[f][r] - mx[r]);
      sacc[f][r] = p;
      sum[r] += p;
    }
#pragma unroll
  for (int r = 0; r < 4; r++)
#pragma unroll
    for (int d = 1; d < 16; d <<= 1) sum[r] += __shfl_xor(sum[r], d);
  float rin[4];
#pragma unroll
  for (int r = 0; r < 4; r++) rin[r] = 1.f / sum[r];
  // write P (normalized probs, bf16) swizzled
#pragma unroll
  for (int r = 0; r < 4; r++) {
    int q = (wid << 4) + (lhi << 2) + r;
    char* pb = (char*)P + (q << 9);
    int sw = (q & 7) << 4;
#pragma unroll
    for (int f = 0; f < 16; f++) {
      int key = ((f >> 2) << 6) + ((f & 3) << 4) + llo;
      *reinterpret_cast<u16*>(pb + ((key << 1) ^ sw)) = f2bf(sacc[f][r] * rin[r]);
    }
  }
  // PV: ctx^T[d][q] = sum_s V[s][d] * P[q][s]
  f32x4 cacc[16] = {};
#pragma unroll 1
  for (int kt = 0; kt < 4; kt++) {
    __syncthreads();
    // stage Vt tile [256 d][64 s], row = 128B = 8 granules, src pre-swizzled g^(d&7)
#pragma unroll
    for (int i = 0; i < 8; i++) {
      int G = (i << 8) + t;
      int d = G >> 3, g = G & 7;
      int gs = g ^ (d & 7);
      const u16* src = vT + ((size_t)((b << 4) + h) * 256 + d) * 256 + (kt << 6) + (gs << 3);
      GLOAD_LDS16(src, (char*)KV + (G << 4));
    }
    __syncthreads();
    bf16x8 pf[2];
    {
      int q = (wid << 4) + llo;
      const char* pb = (const char*)P + (q << 9);
      int sw = (q & 7) << 4;
#pragma unroll
      for (int c = 0; c < 2; c++)
        pf[c] = *reinterpret_cast<const bf16x8*>(pb + (((kt << 7) + (c << 6) + (lhi << 4)) ^ sw));
    }
#pragma unroll
    for (int mf = 0; mf < 16; mf++) {
      int dl = (mf << 4) + llo;
      const char* vb = (const char*)KV + (dl << 7);
      int sw = (dl & 7) << 4;
#pragma unroll
      for (int c = 0; c < 2; c++) {
        bf16x8 vf = *reinterpret_cast<const bf16x8*>(vb + (((lhi << 4) + (c << 6)) ^ sw));
        cacc[mf] = MFMA16(vf, pf[c], cacc[mf]);
      }
    }
  }
  // write ctx[token][h*256 + d] bf16; token = base + llo (col), d = mf*16 + lhi*4 + r (row)
  int token = (b << 8) + (qt << 6) + (wid << 4) + llo;
  u16* crow = ctx + (size_t)token * 4096 + (h << 8);
#pragma unroll
  for (int mf = 0; mf < 16; mf++) {
    ushort4 u;
    u.x = f2bf(cacc[mf][0]); u.y = f2bf(cacc[mf][1]);
    u.z = f2bf(cacc[mf][2]); u.w = f2bf(cacc[mf][3]);
    *reinterpret_cast<ushort4*>(crow + (mf << 4) + (lhi << 2)) = u;
  }
}

extern "C" void kernel_launch(void* const* d_in, const int* in_sizes, int n_in,
                              void* d_out, int out_size, void* d_ws, size_t ws_size,
                              hipStream_t stream) {
  const float* inp  = (const float*)d_in[0];
  const int*   mask = (const int*)d_in[1];
  const float* w    = (const float*)d_in[2];
  const float* bia  = (const float*)d_in[3];
  const float* qkvw = (const float*)d_in[4];
  const float* ow   = (const float*)d_in[5];
  const size_t MB = 1024ull * 1024ull;
  if (ws_size < 352 * MB) return;  // ws layout below needs 352 MiB
  char* ws = (char*)d_ws;
  u16* xn   = (u16*)(ws);             // 64 MiB  [0,64)
  u16* qkvT = (u16*)(ws + 64 * MB);   // 96 MiB  [64,160)
  u16* qk   = (u16*)(ws + 160 * MB);  // 128 MiB [160,288): [8192 tok][8192] (q cols 0..4095, k cols 4096..8191)
  u16* vT   = (u16*)(ws + 288 * MB);  // 64 MiB  [288,352): [b][h][d][s]
  u16* oT   = (u16*)(ws + 64 * MB);   // overlays qkvT (dead after QKV GEMM)
  u16* ctx  = (u16*)(ws);             // overlays xn (dead after QKV GEMM)
  float* out = (float*)d_out;

  transpose_bf16<<<49152, 256, 0, stream>>>(qkvw, qkvT, 4096, 12288);
  ln_bf16<<<8192, 256, 0, stream>>>(inp, w, bia, xn);
  gemm_bt<1><<<6144, 256, 0, stream>>>(xn, qkvT, (void*)qk, vT, 8192, 12288, 4096, 96);
  transpose_bf16<<<16384, 256, 0, stream>>>(ow, oT, 4096, 4096);
  attn_kernel<<<2048, 256, 0, stream>>>(qk, vT, mask, ctx);
  gemm_bt<2><<<2048, 256, 0, stream>>>(ctx, oT, (void*)out, nullptr, 8192, 4096, 4096, 32);
}

// Round 2
// 1317.668 us; speedup vs baseline: 1.4048x; 1.4048x over previous
//
#include <hip/hip_runtime.h>
#include <stdint.h>

typedef unsigned short u16;
typedef short bf16x8 __attribute__((ext_vector_type(8)));
typedef float f32x4 __attribute__((ext_vector_type(4)));

#define MFMA16(a, b, c) __builtin_amdgcn_mfma_f32_16x16x32_bf16((a), (b), (c), 0, 0, 0)

#define GLOAD_LDS16(gp, lp)                                                        \
  __builtin_amdgcn_global_load_lds((const __attribute__((address_space(1))) void*)(gp), \
                                   (__attribute__((address_space(3))) void*)(lp), 16, 0, 0)

#define BARRIER asm volatile("s_barrier" ::: "memory")
#define WAITV(n) asm volatile("s_waitcnt vmcnt(" #n ")" ::: "memory")

__device__ __forceinline__ u16 f2bf(float x) {
  union { float f; uint32_t u; } v; v.f = x;
  uint32_t r = (v.u + 0x7FFFu + ((v.u >> 16) & 1u)) >> 16;
  return (u16)r;
}

// ---------------- transpose + fp32->bf16 convert: in[R][C] f32 -> out[C][R] bf16
__global__ __launch_bounds__(256) void transpose_bf16(const float* __restrict__ in,
                                                      u16* __restrict__ out, int R, int C) {
  __shared__ float tile[32][33];
  int nCt = C >> 5;
  int bid = blockIdx.x;
  int r0 = (bid / nCt) << 5, c0 = (bid % nCt) << 5;
  int t = threadIdx.x;
  int r = t >> 3, cc = (t & 7) << 2;
  float4 v = *reinterpret_cast<const float4*>(in + (size_t)(r0 + r) * C + c0 + cc);
  tile[r][cc] = v.x; tile[r][cc + 1] = v.y; tile[r][cc + 2] = v.z; tile[r][cc + 3] = v.w;
  __syncthreads();
  int c = t >> 3, rr = (t & 7) << 2;
  ushort4 u;
  u.x = f2bf(tile[rr][c]);     u.y = f2bf(tile[rr + 1][c]);
  u.z = f2bf(tile[rr + 2][c]); u.w = f2bf(tile[rr + 3][c]);
  *reinterpret_cast<ushort4*>(out + (size_t)(c0 + c) * R + r0 + rr) = u;
}

// ---------------- LayerNorm (H=4096) -> bf16
__global__ __launch_bounds__(256) void ln_bf16(const float* __restrict__ in,
                                               const float* __restrict__ w,
                                               const float* __restrict__ bia,
                                               u16* __restrict__ out) {
  int row = blockIdx.x, t = threadIdx.x;
  const float* x = in + (size_t)row * 4096;
  float4 v[4];
  float s = 0.f, sq = 0.f;
#pragma unroll
  for (int i = 0; i < 4; i++) {
    v[i] = *reinterpret_cast<const float4*>(x + i * 1024 + t * 4);
    s  += v[i].x + v[i].y + v[i].z + v[i].w;
    sq += v[i].x * v[i].x + v[i].y * v[i].y + v[i].z * v[i].z + v[i].w * v[i].w;
  }
#pragma unroll
  for (int off = 32; off > 0; off >>= 1) { s += __shfl_down(s, off); sq += __shfl_down(sq, off); }
  __shared__ float red[8];
  int wid = t >> 6, lane = t & 63;
  if (lane == 0) { red[wid] = s; red[4 + wid] = sq; }
  __syncthreads();
  if (t == 0) {
    float st = red[0] + red[1] + red[2] + red[3];
    float sqt = red[4] + red[5] + red[6] + red[7];
    float mu = st * (1.f / 4096.f);
    float var = sqt * (1.f / 4096.f) - mu * mu;
    red[0] = mu; red[1] = rsqrtf(var + 1e-5f);
  }
  __syncthreads();
  float mu = red[0], rs = red[1];
#pragma unroll
  for (int i = 0; i < 4; i++) {
    float4 wv = *reinterpret_cast<const float4*>(w + i * 1024 + t * 4);
    float4 bv = *reinterpret_cast<const float4*>(bia + i * 1024 + t * 4);
    ushort4 u;
    u.x = f2bf((v[i].x - mu) * rs * wv.x + bv.x);
    u.y = f2bf((v[i].y - mu) * rs * wv.y + bv.y);
    u.z = f2bf((v[i].z - mu) * rs * wv.z + bv.z);
    u.w = f2bf((v[i].w - mu) * rs * wv.w + bv.w);
    *reinterpret_cast<ushort4*>(out + (size_t)row * 4096 + i * 1024 + t * 4) = u;
  }
}

// ======================= 256x256 8-phase GEMM (T1+T2+T3+T4+T5) =======================
// C[M][N] = A[M][K] * Bt[N][K]^T, bf16 in, fp32 acc. 512 threads = 8 waves (2M x 4N).
// LDS 128 KiB: 2 buffers x (A[256][64] + B[256][64]) bf16, rows of 128B,
// XOR-swizzled (byte ^= (row&7)<<4) via pre-swizzled global source.
// Row placement permutations make each consumption-half a contiguous 16 KiB region:
//   A: lds_row = swap bits6,7 of tile row; B: tile bit5 -> lds bit7, bits7:6 -> 6:5.
// Phase waits: vmcnt(4) (counted, never 0 in main loop); epilogue drains 4->2->0.

#define LDA8(AR, Ab, mh) do {                                                     \
  _Pragma("unroll")                                                               \
  for (int mf = 0; mf < 4; mf++) {                                                \
    int lr = (mh)*128 + wm64 + mf*16 + llo;                                       \
    const char* rb = (Ab) + lr*128;                                               \
    int sw = (lr & 7) << 4;                                                       \
    AR[mf*2+0] = *reinterpret_cast<const bf16x8*>(rb + ((lhi16) ^ sw));           \
    AR[mf*2+1] = *reinterpret_cast<const bf16x8*>(rb + ((64 + lhi16) ^ sw));      \
  }                                                                               \
} while (0)

#define LDB4(BR, Bb, nh) do {                                                     \
  _Pragma("unroll")                                                               \
  for (int nf = 0; nf < 2; nf++) {                                                \
    int lr = (nh)*128 + wn32 + nf*16 + llo;                                       \
    const char* rb = (Bb) + lr*128;                                               \
    int sw = (lr & 7) << 4;                                                       \
    BR[nf*2+0] = *reinterpret_cast<const bf16x8*>(rb + ((lhi16) ^ sw));           \
    BR[nf*2+1] = *reinterpret_cast<const bf16x8*>(rb + ((64 + lhi16) ^ sw));      \
  }                                                                               \
} while (0)

#define MMAQ(AR, BR, mh, nh) do {                                                 \
  __builtin_amdgcn_s_setprio(1);                                                  \
  _Pragma("unroll")                                                               \
  for (int mf = 0; mf < 4; mf++)                                                  \
    _Pragma("unroll")                                                             \
    for (int nf = 0; nf < 2; nf++) {                                              \
      acc[(mh)*4+mf][(nh)*2+nf] = MFMA16(AR[mf*2+0], BR[nf*2+0], acc[(mh)*4+mf][(nh)*2+nf]); \
      acc[(mh)*4+mf][(nh)*2+nf] = MFMA16(AR[mf*2+1], BR[nf*2+1], acc[(mh)*4+mf][(nh)*2+nf]); \
    }                                                                             \
  __builtin_amdgcn_s_setprio(0);                                                  \
} while (0)

// stage one 16-KiB half-tile (2 x global_load_lds per thread), linear LDS dest,
// inverse-swizzled + row-permuted global source.
#define STAGE(isB, h, cbuf, ktile) do {                                           \
  const u16* g_ = (isB) ? Bt : A;                                                 \
  int base0_ = (isB) ? n0 : m0;                                                   \
  char* lb_ = smc + (cbuf)*65536 + (isB)*32768 + (h)*16384;                       \
  _Pragma("unroll")                                                               \
  for (int i_ = 0; i_ < 2; i_++) {                                                \
    int L_ = i_*512 + t;                                                          \
    int lr_ = (h)*128 + (L_ >> 3);                                                \
    int sl_ = (L_ & 7) ^ (lr_ & 7);                                               \
    int r_ = (isB) ? (((lr_ & 128) >> 2) | ((lr_ & 96) << 1) | (lr_ & 31))        \
                   : ((lr_ & 63) | ((lr_ & 64) << 1) | ((lr_ & 128) >> 1));       \
    GLOAD_LDS16(g_ + (size_t)(base0_ + r_) * K + (ktile)*64 + sl_*8, lb_ + L_*16);\
  }                                                                               \
} while (0)

template <int EPI>
__global__ __launch_bounds__(512, 2) void gemm256(const u16* __restrict__ A, const u16* __restrict__ Bt,
                                                  void* __restrict__ Cout, u16* __restrict__ vT,
                                                  int M, int N, int K, int nbn) {
  __shared__ u16 sm[65536];  // 128 KiB
  char* smc = (char*)sm;
  int nwg = gridDim.x;
  int bid = blockIdx.x;
  int wg = ((bid & 7) * (nwg >> 3)) + (bid >> 3);  // XCD-bijective (nwg % 8 == 0)
  int tm = wg / nbn, tn = wg % nbn;
  int m0 = tm << 8, n0 = tn << 8;
  int t = threadIdx.x;
  int w = t >> 6, lane = t & 63;
  int wm = w >> 2, wn = w & 3;
  int llo = lane & 15, lhi = lane >> 4;
  int wm64 = wm << 6, wn32 = wn << 5, lhi16 = lhi << 4;
  f32x4 acc[8][4] = {};
  bf16x8 aR[8], b0R[4], b1R[4];
  int NT = K >> 6;
  // prologue: stage tile 0 halves in consumption order A0,B0,B1,A1
  STAGE(0, 0, 0, 0); STAGE(1, 0, 0, 0); STAGE(1, 1, 0, 0); STAGE(0, 1, 0, 0);
  WAITV(4); BARRIER;
#pragma unroll 1
  for (int kt = 0; kt < NT - 1; kt++) {
    int c = kt & 1, cn = c ^ 1;
    const char* Ab = smc + c * 65536;
    const char* Bb = Ab + 32768;
    // P0: quadrant (0,0)
    LDA8(aR, Ab, 0); LDB4(b0R, Bb, 0);
    STAGE(0, 0, cn, kt + 1);
    BARRIER;
    MMAQ(aR, b0R, 0, 0);
    WAITV(4); BARRIER;
    // P1: quadrant (0,1)
    LDB4(b1R, Bb, 1);
    STAGE(1, 0, cn, kt + 1);
    BARRIER;
    MMAQ(aR, b1R, 0, 1);
    WAITV(4); BARRIER;
    // P2: quadrant (1,1)
    LDA8(aR, Ab, 1);
    STAGE(1, 1, cn, kt + 1);
    BARRIER;
    MMAQ(aR, b1R, 1, 1);
    BARRIER;
    // P3: quadrant (1,0) (regs only)
    STAGE(0, 1, cn, kt + 1);
    BARRIER;
    MMAQ(aR, b0R, 1, 0);
    WAITV(4); BARRIER;
  }
  {  // last tile: drain 4 -> 2 -> 0
    int c = (NT - 1) & 1;
    const char* Ab = smc + c * 65536;
    const char* Bb = Ab + 32768;
    LDA8(aR, Ab, 0); LDB4(b0R, Bb, 0);
    MMAQ(aR, b0R, 0, 0);
    WAITV(2); BARRIER;
    LDB4(b1R, Bb, 1);
    MMAQ(aR, b1R, 0, 1);
    WAITV(0); BARRIER;
    LDA8(aR, Ab, 1);
    MMAQ(aR, b1R, 1, 1);
    MMAQ(aR, b0R, 1, 0);
  }
  // ---- epilogue ----
  if (EPI == 2) {
    float* C = (float*)Cout;
#pragma unroll
    for (int mi = 0; mi < 8; mi++)
#pragma unroll
      for (int ni = 0; ni < 4; ni++) {
        int m = m0 + wm * 128 + mi * 16 + lhi * 4;
        int n = n0 + wn * 64 + ni * 16 + llo;
#pragma unroll
        for (int r = 0; r < 4; r++) C[(size_t)(m + r) * N + n] = acc[mi][ni][r];
      }
  } else {
    if (n0 < 8192) {
      u16* qkb = (u16*)Cout;
#pragma unroll
      for (int mi = 0; mi < 8; mi++)
#pragma unroll
        for (int ni = 0; ni < 4; ni++) {
          int m = m0 + wm * 128 + mi * 16 + lhi * 4;
          int n = n0 + wn * 64 + ni * 16 + llo;
#pragma unroll
          for (int r = 0; r < 4; r++) qkb[(size_t)(m + r) * 8192 + n] = f2bf(acc[mi][ni][r]);
        }
    } else {
#pragma unroll
      for (int mi = 0; mi < 8; mi++)
#pragma unroll
        for (int ni = 0; ni < 4; ni++) {
          int m = m0 + wm * 128 + mi * 16 + lhi * 4;
          int n_ = n0 + wn * 64 + ni * 16 + llo - 8192;
          int h = n_ >> 8, d = n_ & 255;
          int b = m >> 8, s = m & 255;
          ushort4 u;
          u.x = f2bf(acc[mi][ni][0]); u.y = f2bf(acc[mi][ni][1]);
          u.z = f2bf(acc[mi][ni][2]); u.w = f2bf(acc[mi][ni][3]);
          *reinterpret_cast<ushort4*>(vT + ((size_t)((b << 4) + h) * 256 + d) * 256 + s) = u;
        }
    }
  }
}

// ---------------- attention: block = (b, h, 64 q-rows); 4 waves, each 16 q-rows
__global__ __launch_bounds__(256) void attn_kernel(const u16* __restrict__ qk,
                                                   const u16* __restrict__ vT,
                                                   const int* __restrict__ mask,
                                                   u16* __restrict__ ctx) {
  __shared__ u16 KV[64 * 256];   // 32 KiB: K tiles, then Vt tiles (swizzled rows)
  __shared__ u16 P[64 * 256];    // 32 KiB: probs [64 q][256 key] (swizzled rows)
  __shared__ float maskf[256];
  int bx = blockIdx.x;
  int qt = bx & 3, h = (bx >> 2) & 15, b = bx >> 6;
  int t = threadIdx.x, wid = t >> 6, lane = t & 63, llo = lane & 15, lhi = lane >> 4;
  maskf[t] = mask[(b << 8) + t] ? -1e30f : 0.0f;
  bf16x8 qf[8];
  {
    const u16* qrow = qk + (size_t)((b << 8) + (qt << 6) + (wid << 4) + llo) * 8192 + (h << 8);
#pragma unroll
    for (int c = 0; c < 8; c++)
      qf[c] = *reinterpret_cast<const bf16x8*>(qrow + (lhi << 3) + (c << 5));
  }
  f32x4 sacc[16] = {};
#pragma unroll 1
  for (int kt = 0; kt < 4; kt++) {
    __syncthreads();
#pragma unroll
    for (int i = 0; i < 8; i++) {
      int G = (i << 8) + t;
      int key = G >> 5, g = G & 31;
      int gs = g ^ (key & 7);
      const u16* src = qk + (size_t)((b << 8) + (kt << 6) + key) * 8192 + 4096 + (h << 8) + (gs << 3);
      GLOAD_LDS16(src, (char*)KV + (G << 4));
    }
    __syncthreads();
#pragma unroll
    for (int nf = 0; nf < 4; nf++) {
      int kl = (nf << 4) + llo;
      const char* kb = (const char*)KV + (kl << 9);
      int sw = (kl & 7) << 4;
#pragma unroll
      for (int c = 0; c < 8; c++) {
        bf16x8 kf = *reinterpret_cast<const bf16x8*>(kb + (((lhi << 4) + (c << 6)) ^ sw));
        sacc[kt * 4 + nf] = MFMA16(qf[c], kf, sacc[kt * 4 + nf]);
      }
    }
  }
  float madd[16];
#pragma unroll
  for (int f = 0; f < 16; f++)
    madd[f] = maskf[((f >> 2) << 6) + ((f & 3) << 4) + llo];
  float mx[4] = {-3e38f, -3e38f, -3e38f, -3e38f};
#pragma unroll
  for (int f = 0; f < 16; f++)
#pragma unroll
    for (int r = 0; r < 4; r++) {
      float sv = sacc[f][r] * 0.0625f + madd[f];
      sacc[f][r] = sv;
      mx[r] = fmaxf(mx[r], sv);
    }
#pragma unroll
  for (int r = 0; r < 4; r++)
#pragma unroll
    for (int d = 1; d < 16; d <<= 1) mx[r] = fmaxf(mx[r], __shfl_xor(mx[r], d));
  float sum[4] = {0.f, 0.f, 0.f, 0.f};
#pragma unroll
  for (int f = 0; f < 16; f++)
#pragma unroll
    for (int r = 0; r < 4; r++) {
      float p = __expf(sacc[f][r] - mx[r]);
      sacc[f][r] = p;
      sum[r] += p;
    }
#pragma unroll
  for (int r = 0; r < 4; r++)
#pragma unroll
    for (int d = 1; d < 16; d <<= 1) sum[r] += __shfl_xor(sum[r], d);
  float rin[4];
#pragma unroll
  for (int r = 0; r < 4; r++) rin[r] = 1.f / sum[r];
#pragma unroll
  for (int r = 0; r < 4; r++) {
    int q = (wid << 4) + (lhi << 2) + r;
    char* pb = (char*)P + (q << 9);
    int sw = (q & 7) << 4;
#pragma unroll
    for (int f = 0; f < 16; f++) {
      int key = ((f >> 2) << 6) + ((f & 3) << 4) + llo;
      *reinterpret_cast<u16*>(pb + ((key << 1) ^ sw)) = f2bf(sacc[f][r] * rin[r]);
    }
  }
  f32x4 cacc[16] = {};
#pragma unroll 1
  for (int kt = 0; kt < 4; kt++) {
    __syncthreads();
#pragma unroll
    for (int i = 0; i < 8; i++) {
      int G = (i << 8) + t;
      int d = G >> 3, g = G & 7;
      int gs = g ^ (d & 7);
      const u16* src = vT + ((size_t)((b << 4) + h) * 256 + d) * 256 + (kt << 6) + (gs << 3);
      GLOAD_LDS16(src, (char*)KV + (G << 4));
    }
    __syncthreads();
    bf16x8 pf[2];
    {
      int q = (wid << 4) + llo;
      const char* pb = (const char*)P + (q << 9);
      int sw = (q & 7) << 4;
#pragma unroll
      for (int c = 0; c < 2; c++)
        pf[c] = *reinterpret_cast<const bf16x8*>(pb + (((kt << 7) + (c << 6) + (lhi << 4)) ^ sw));
    }
#pragma unroll
    for (int mf = 0; mf < 16; mf++) {
      int dl = (mf << 4) + llo;
      const char* vb = (const char*)KV + (dl << 7);
      int sw = (dl & 7) << 4;
#pragma unroll
      for (int c = 0; c < 2; c++) {
        bf16x8 vf = *reinterpret_cast<const bf16x8*>(vb + (((lhi << 4) + (c << 6)) ^ sw));
        cacc[mf] = MFMA16(vf, pf[c], cacc[mf]);
      }
    }
  }
  int token = (b << 8) + (qt << 6) + (wid << 4) + llo;
  u16* crow = ctx + (size_t)token * 4096 + (h << 8);
#pragma unroll
  for (int mf = 0; mf < 16; mf++) {
    ushort4 u;
    u.x = f2bf(cacc[mf][0]); u.y = f2bf(cacc[mf][1]);
    u.z = f2bf(cacc[mf][2]); u.w = f2bf(cacc[mf][3]);
    *reinterpret_cast<ushort4*>(crow + (mf << 4) + (lhi << 2)) = u;
  }
}

extern "C" void kernel_launch(void* const* d_in, const int* in_sizes, int n_in,
                              void* d_out, int out_size, void* d_ws, size_t ws_size,
                              hipStream_t stream) {
  const float* inp  = (const float*)d_in[0];
  const int*   mask = (const int*)d_in[1];
  const float* w    = (const float*)d_in[2];
  const float* bia  = (const float*)d_in[3];
  const float* qkvw = (const float*)d_in[4];
  const float* ow   = (const float*)d_in[5];
  const size_t MB = 1024ull * 1024ull;
  if (ws_size < 352 * MB) return;  // ws layout below needs 352 MiB
  char* ws = (char*)d_ws;
  u16* xn   = (u16*)(ws);             // 64 MiB  [0,64)
  u16* qkvT = (u16*)(ws + 64 * MB);   // 96 MiB  [64,160)
  u16* qk   = (u16*)(ws + 160 * MB);  // 128 MiB [160,288): [8192 tok][8192]
  u16* vT   = (u16*)(ws + 288 * MB);  // 64 MiB  [288,352): [b][h][d][s]
  u16* oT   = (u16*)(ws + 64 * MB);   // overlays qkvT (dead after QKV GEMM)
  u16* ctx  = (u16*)(ws);             // overlays xn (dead after QKV GEMM)
  float* out = (float*)d_out;

  transpose_bf16<<<49152, 256, 0, stream>>>(qkvw, qkvT, 4096, 12288);
  ln_bf16<<<8192, 256, 0, stream>>>(inp, w, bia, xn);
  gemm256<1><<<1536, 512, 0, stream>>>(xn, qkvT, (void*)qk, vT, 8192, 12288, 4096, 48);
  transpose_bf16<<<16384, 256, 0, stream>>>(ow, oT, 4096, 4096);
  attn_kernel<<<2048, 256, 0, stream>>>(qk, vT, mask, ctx);
  gemm256<2><<<512, 512, 0, stream>>>(ctx, oT, (void*)out, nullptr, 8192, 4096, 4096, 16);
}

// Round 3
// 1294.967 us; speedup vs baseline: 1.4294x; 1.0175x over previous
//
#include <hip/hip_runtime.h>
#include <stdint.h>

typedef unsigned short u16;
typedef short bf16x8 __attribute__((ext_vector_type(8)));
typedef float f32x4 __attribute__((ext_vector_type(4)));

#define MFMA16(a, b, c) __builtin_amdgcn_mfma_f32_16x16x32_bf16((a), (b), (c), 0, 0, 0)

#define GLOAD_LDS16(gp, lp)                                                        \
  __builtin_amdgcn_global_load_lds((const __attribute__((address_space(1))) void*)(gp), \
                                   (__attribute__((address_space(3))) void*)(lp), 16, 0, 0)

#define BARRIER asm volatile("s_barrier" ::: "memory")
#define WAITV(n) asm volatile("s_waitcnt vmcnt(" #n ")" ::: "memory")

__device__ __forceinline__ u16 f2bf(float x) {
  union { float f; uint32_t u; } v; v.f = x;
  uint32_t r = (v.u + 0x7FFFu + ((v.u >> 16) & 1u)) >> 16;
  return (u16)r;
}

// ---------------- transpose + fp32->bf16 convert: in[R][C] f32 -> out[C][R] bf16
__global__ __launch_bounds__(256) void transpose_bf16(const float* __restrict__ in,
                                                      u16* __restrict__ out, int R, int C) {
  __shared__ float tile[32][33];
  int nCt = C >> 5;
  int bid = blockIdx.x;
  int r0 = (bid / nCt) << 5, c0 = (bid % nCt) << 5;
  int t = threadIdx.x;
  int r = t >> 3, cc = (t & 7) << 2;
  float4 v = *reinterpret_cast<const float4*>(in + (size_t)(r0 + r) * C + c0 + cc);
  tile[r][cc] = v.x; tile[r][cc + 1] = v.y; tile[r][cc + 2] = v.z; tile[r][cc + 3] = v.w;
  __syncthreads();
  int c = t >> 3, rr = (t & 7) << 2;
  ushort4 u;
  u.x = f2bf(tile[rr][c]);     u.y = f2bf(tile[rr + 1][c]);
  u.z = f2bf(tile[rr + 2][c]); u.w = f2bf(tile[rr + 3][c]);
  *reinterpret_cast<ushort4*>(out + (size_t)(c0 + c) * R + r0 + rr) = u;
}

// ---------------- LayerNorm (H=4096) -> bf16
__global__ __launch_bounds__(256) void ln_bf16(const float* __restrict__ in,
                                               const float* __restrict__ w,
                                               const float* __restrict__ bia,
                                               u16* __restrict__ out) {
  int row = blockIdx.x, t = threadIdx.x;
  const float* x = in + (size_t)row * 4096;
  float4 v[4];
  float s = 0.f, sq = 0.f;
#pragma unroll
  for (int i = 0; i < 4; i++) {
    v[i] = *reinterpret_cast<const float4*>(x + i * 1024 + t * 4);
    s  += v[i].x + v[i].y + v[i].z + v[i].w;
    sq += v[i].x * v[i].x + v[i].y * v[i].y + v[i].z * v[i].z + v[i].w * v[i].w;
  }
#pragma unroll
  for (int off = 32; off > 0; off >>= 1) { s += __shfl_down(s, off); sq += __shfl_down(sq, off); }
  __shared__ float red[8];
  int wid = t >> 6, lane = t & 63;
  if (lane == 0) { red[wid] = s; red[4 + wid] = sq; }
  __syncthreads();
  if (t == 0) {
    float st = red[0] + red[1] + red[2] + red[3];
    float sqt = red[4] + red[5] + red[6] + red[7];
    float mu = st * (1.f / 4096.f);
    float var = sqt * (1.f / 4096.f) - mu * mu;
    red[0] = mu; red[1] = rsqrtf(var + 1e-5f);
  }
  __syncthreads();
  float mu = red[0], rs = red[1];
#pragma unroll
  for (int i = 0; i < 4; i++) {
    float4 wv = *reinterpret_cast<const float4*>(w + i * 1024 + t * 4);
    float4 bv = *reinterpret_cast<const float4*>(bia + i * 1024 + t * 4);
    ushort4 u;
    u.x = f2bf((v[i].x - mu) * rs * wv.x + bv.x);
    u.y = f2bf((v[i].y - mu) * rs * wv.y + bv.y);
    u.z = f2bf((v[i].z - mu) * rs * wv.z + bv.z);
    u.w = f2bf((v[i].w - mu) * rs * wv.w + bv.w);
    *reinterpret_cast<ushort4*>(out + (size_t)row * 4096 + i * 1024 + t * 4) = u;
  }
}

// ======================= 256x256 8-phase GEMM (T1+T2+T3+T4+T5) =======================
// C[M][N] = A[M][K] * Bt[N][K]^T, bf16 in, fp32 acc. 512 threads = 8 waves (2M x 4N).
// LDS 128 KiB: 2 buffers x (A[256][64] + B[256][64]) bf16, rows of 128B,
// XOR-swizzled (byte ^= (row&7)<<4) via pre-swizzled global source.
// Supertile raster: 256 consecutive blocks (the resident set) cover a 16x16-tile
// supertile (64 MB A+B working set -> L3-resident); each XCD (bid%8) owns a 4x8
// sub-rect for L2 locality. Requires nbm%16==0, nbn%16==0, grid%256==0.
// Phase waits: vmcnt(4) (counted, never 0 in main loop); epilogue drains 4->2->0.

#define LDA8(AR, Ab, mh) do {                                                     \
  _Pragma("unroll")                                                               \
  for (int mf = 0; mf < 4; mf++) {                                                \
    int lr = (mh)*128 + wm64 + mf*16 + llo;                                       \
    const char* rb = (Ab) + lr*128;                                               \
    int sw = (lr & 7) << 4;                                                       \
    AR[mf*2+0] = *reinterpret_cast<const bf16x8*>(rb + ((lhi16) ^ sw));           \
    AR[mf*2+1] = *reinterpret_cast<const bf16x8*>(rb + ((64 + lhi16) ^ sw));      \
  }                                                                               \
} while (0)

#define LDB4(BR, Bb, nh) do {                                                     \
  _Pragma("unroll")                                                               \
  for (int nf = 0; nf < 2; nf++) {                                                \
    int lr = (nh)*128 + wn32 + nf*16 + llo;                                       \
    const char* rb = (Bb) + lr*128;                                               \
    int sw = (lr & 7) << 4;                                                       \
    BR[nf*2+0] = *reinterpret_cast<const bf16x8*>(rb + ((lhi16) ^ sw));           \
    BR[nf*2+1] = *reinterpret_cast<const bf16x8*>(rb + ((64 + lhi16) ^ sw));      \
  }                                                                               \
} while (0)

#define MMAQ(AR, BR, mh, nh) do {                                                 \
  __builtin_amdgcn_s_setprio(1);                                                  \
  _Pragma("unroll")                                                               \
  for (int mf = 0; mf < 4; mf++)                                                  \
    _Pragma("unroll")                                                             \
    for (int nf = 0; nf < 2; nf++) {                                              \
      acc[(mh)*4+mf][(nh)*2+nf] = MFMA16(AR[mf*2+0], BR[nf*2+0], acc[(mh)*4+mf][(nh)*2+nf]); \
      acc[(mh)*4+mf][(nh)*2+nf] = MFMA16(AR[mf*2+1], BR[nf*2+1], acc[(mh)*4+mf][(nh)*2+nf]); \
    }                                                                             \
  __builtin_amdgcn_s_setprio(0);                                                  \
} while (0)

// stage one 16-KiB half-tile (2 x global_load_lds per thread), linear LDS dest,
// inverse-swizzled + row-permuted global source.
#define STAGE(isB, h, cbuf, ktile) do {                                           \
  const u16* g_ = (isB) ? Bt : A;                                                 \
  int base0_ = (isB) ? n0 : m0;                                                   \
  char* lb_ = smc + (cbuf)*65536 + (isB)*32768 + (h)*16384;                       \
  _Pragma("unroll")                                                               \
  for (int i_ = 0; i_ < 2; i_++) {                                                \
    int L_ = i_*512 + t;                                                          \
    int lr_ = (h)*128 + (L_ >> 3);                                                \
    int sl_ = (L_ & 7) ^ (lr_ & 7);                                               \
    int r_ = (isB) ? (((lr_ & 128) >> 2) | ((lr_ & 96) << 1) | (lr_ & 31))        \
                   : ((lr_ & 63) | ((lr_ & 64) << 1) | ((lr_ & 128) >> 1));       \
    GLOAD_LDS16(g_ + (size_t)(base0_ + r_) * K + (ktile)*64 + sl_*8, lb_ + L_*16);\
  }                                                                               \
} while (0)

template <int EPI>
__global__ __launch_bounds__(512, 2) void gemm256(const u16* __restrict__ A, const u16* __restrict__ Bt,
                                                  void* __restrict__ Cout, u16* __restrict__ vT,
                                                  int M, int N, int K, int nbn) {
  __shared__ u16 sm[65536];  // 128 KiB
  char* smc = (char*)sm;
  int bid = blockIdx.x;
  // --- supertile raster (16x16 tiles per 256 blocks; XCD 4x8 sub-rect) ---
  int s = bid >> 8, local = bid & 255;
  int xcd = local & 7, j = local >> 3;
  int trow = ((xcd >> 1) << 2) + (j >> 3);   // 0..15
  int tcol = ((xcd & 1) << 3) + (j & 7);     // 0..15
  int nsc = nbn >> 4;
  int sr = s / nsc, sc = s - sr * nsc;
  int tm = (sr << 4) + trow, tn = (sc << 4) + tcol;
  int m0 = tm << 8, n0 = tn << 8;
  int t = threadIdx.x;
  int w = t >> 6, lane = t & 63;
  int wm = w >> 2, wn = w & 3;
  int llo = lane & 15, lhi = lane >> 4;
  int wm64 = wm << 6, wn32 = wn << 5, lhi16 = lhi << 4;
  f32x4 acc[8][4] = {};
  bf16x8 aR[8], b0R[4], b1R[4];
  int NT = K >> 6;
  // prologue: stage tile 0 halves in consumption order A0,B0,B1,A1
  STAGE(0, 0, 0, 0); STAGE(1, 0, 0, 0); STAGE(1, 1, 0, 0); STAGE(0, 1, 0, 0);
  WAITV(4); BARRIER;
#pragma unroll 1
  for (int kt = 0; kt < NT - 1; kt++) {
    int c = kt & 1, cn = c ^ 1;
    const char* Ab = smc + c * 65536;
    const char* Bb = Ab + 32768;
    // P0: quadrant (0,0)
    LDA8(aR, Ab, 0); LDB4(b0R, Bb, 0);
    STAGE(0, 0, cn, kt + 1);
    BARRIER;
    MMAQ(aR, b0R, 0, 0);
    WAITV(4); BARRIER;
    // P1: quadrant (0,1)
    LDB4(b1R, Bb, 1);
    STAGE(1, 0, cn, kt + 1);
    BARRIER;
    MMAQ(aR, b1R, 0, 1);
    WAITV(4); BARRIER;
    // P2: quadrant (1,1)
    LDA8(aR, Ab, 1);
    STAGE(1, 1, cn, kt + 1);
    BARRIER;
    MMAQ(aR, b1R, 1, 1);
    BARRIER;
    // P3: quadrant (1,0) (regs only)
    STAGE(0, 1, cn, kt + 1);
    BARRIER;
    MMAQ(aR, b0R, 1, 0);
    WAITV(4); BARRIER;
  }
  {  // last tile: drain 4 -> 2 -> 0
    int c = (NT - 1) & 1;
    const char* Ab = smc + c * 65536;
    const char* Bb = Ab + 32768;
    LDA8(aR, Ab, 0); LDB4(b0R, Bb, 0);
    MMAQ(aR, b0R, 0, 0);
    WAITV(2); BARRIER;
    LDB4(b1R, Bb, 1);
    MMAQ(aR, b1R, 0, 1);
    WAITV(0); BARRIER;
    LDA8(aR, Ab, 1);
    MMAQ(aR, b1R, 1, 1);
    MMAQ(aR, b0R, 1, 0);
  }
  // ---- epilogue ----
  if (EPI == 2) {
    float* C = (float*)Cout;
#pragma unroll
    for (int mi = 0; mi < 8; mi++)
#pragma unroll
      for (int ni = 0; ni < 4; ni++) {
        int m = m0 + wm * 128 + mi * 16 + lhi * 4;
        int n = n0 + wn * 64 + ni * 16 + llo;
#pragma unroll
        for (int r = 0; r < 4; r++) C[(size_t)(m + r) * N + n] = acc[mi][ni][r];
      }
  } else {
    if (n0 < 8192) {
      u16* qkb = (u16*)Cout;
#pragma unroll
      for (int mi = 0; mi < 8; mi++)
#pragma unroll
        for (int ni = 0; ni < 4; ni++) {
          int m = m0 + wm * 128 + mi * 16 + lhi * 4;
          int n = n0 + wn * 64 + ni * 16 + llo;
#pragma unroll
          for (int r = 0; r < 4; r++) qkb[(size_t)(m + r) * 8192 + n] = f2bf(acc[mi][ni][r]);
        }
    } else {
#pragma unroll
      for (int mi = 0; mi < 8; mi++)
#pragma unroll
        for (int ni = 0; ni < 4; ni++) {
          int m = m0 + wm * 128 + mi * 16 + lhi * 4;
          int n_ = n0 + wn * 64 + ni * 16 + llo - 8192;
          int h = n_ >> 8, d = n_ & 255;
          int b = m >> 8, s2 = m & 255;
          ushort4 u;
          u.x = f2bf(acc[mi][ni][0]); u.y = f2bf(acc[mi][ni][1]);
          u.z = f2bf(acc[mi][ni][2]); u.w = f2bf(acc[mi][ni][3]);
          *reinterpret_cast<ushort4*>(vT + ((size_t)((b << 4) + h) * 256 + d) * 256 + s2) = u;
        }
    }
  }
}

// ---------------- attention: block = (b, h, 64 q-rows); 4 waves, each 16 q-rows
__global__ __launch_bounds__(256) void attn_kernel(const u16* __restrict__ qk,
                                                   const u16* __restrict__ vT,
                                                   const int* __restrict__ mask,
                                                   u16* __restrict__ ctx) {
  __shared__ u16 KV[64 * 256];   // 32 KiB: K tiles, then Vt tiles (swizzled rows)
  __shared__ u16 P[64 * 256];    // 32 KiB: probs [64 q][256 key] (swizzled rows)
  __shared__ float maskf[256];
  int bx = blockIdx.x;
  int qt = bx & 3, h = (bx >> 2) & 15, b = bx >> 6;
  int t = threadIdx.x, wid = t >> 6, lane = t & 63, llo = lane & 15, lhi = lane >> 4;
  maskf[t] = mask[(b << 8) + t] ? -1e30f : 0.0f;
  bf16x8 qf[8];
  {
    const u16* qrow = qk + (size_t)((b << 8) + (qt << 6) + (wid << 4) + llo) * 8192 + (h << 8);
#pragma unroll
    for (int c = 0; c < 8; c++)
      qf[c] = *reinterpret_cast<const bf16x8*>(qrow + (lhi << 3) + (c << 5));
  }
  f32x4 sacc[16] = {};
#pragma unroll 1
  for (int kt = 0; kt < 4; kt++) {
    __syncthreads();
#pragma unroll
    for (int i = 0; i < 8; i++) {
      int G = (i << 8) + t;
      int key = G >> 5, g = G & 31;
      int gs = g ^ (key & 7);
      const u16* src = qk + (size_t)((b << 8) + (kt << 6) + key) * 8192 + 4096 + (h << 8) + (gs << 3);
      GLOAD_LDS16(src, (char*)KV + (G << 4));
    }
    __syncthreads();
#pragma unroll
    for (int nf = 0; nf < 4; nf++) {
      int kl = (nf << 4) + llo;
      const char* kb = (const char*)KV + (kl << 9);
      int sw = (kl & 7) << 4;
#pragma unroll
      for (int c = 0; c < 8; c++) {
        bf16x8 kf = *reinterpret_cast<const bf16x8*>(kb + (((lhi << 4) + (c << 6)) ^ sw));
        sacc[kt * 4 + nf] = MFMA16(qf[c], kf, sacc[kt * 4 + nf]);
      }
    }
  }
  float madd[16];
#pragma unroll
  for (int f = 0; f < 16; f++)
    madd[f] = maskf[((f >> 2) << 6) + ((f & 3) << 4) + llo];
  float mx[4] = {-3e38f, -3e38f, -3e38f, -3e38f};
#pragma unroll
  for (int f = 0; f < 16; f++)
#pragma unroll
    for (int r = 0; r < 4; r++) {
      float sv = sacc[f][r] * 0.0625f + madd[f];
      sacc[f][r] = sv;
      mx[r] = fmaxf(mx[r], sv);
    }
#pragma unroll
  for (int r = 0; r < 4; r++)
#pragma unroll
    for (int d = 1; d < 16; d <<= 1) mx[r] = fmaxf(mx[r], __shfl_xor(mx[r], d));
  float sum[4] = {0.f, 0.f, 0.f, 0.f};
#pragma unroll
  for (int f = 0; f < 16; f++)
#pragma unroll
    for (int r = 0; r < 4; r++) {
      float p = __expf(sacc[f][r] - mx[r]);
      sacc[f][r] = p;
      sum[r] += p;
    }
#pragma unroll
  for (int r = 0; r < 4; r++)
#pragma unroll
    for (int d = 1; d < 16; d <<= 1) sum[r] += __shfl_xor(sum[r], d);
  float rin[4];
#pragma unroll
  for (int r = 0; r < 4; r++) rin[r] = 1.f / sum[r];
#pragma unroll
  for (int r = 0; r < 4; r++) {
    int q = (wid << 4) + (lhi << 2) + r;
    char* pb = (char*)P + (q << 9);
    int sw = (q & 7) << 4;
#pragma unroll
    for (int f = 0; f < 16; f++) {
      int key = ((f >> 2) << 6) + ((f & 3) << 4) + llo;
      *reinterpret_cast<u16*>(pb + ((key << 1) ^ sw)) = f2bf(sacc[f][r] * rin[r]);
    }
  }
  f32x4 cacc[16] = {};
#pragma unroll 1
  for (int kt = 0; kt < 4; kt++) {
    __syncthreads();
#pragma unroll
    for (int i = 0; i < 8; i++) {
      int G = (i << 8) + t;
      int d = G >> 3, g = G & 7;
      int gs = g ^ (d & 7);
      const u16* src = vT + ((size_t)((b << 4) + h) * 256 + d) * 256 + (kt << 6) + (gs << 3);
      GLOAD_LDS16(src, (char*)KV + (G << 4));
    }
    __syncthreads();
    bf16x8 pf[2];
    {
      int q = (wid << 4) + llo;
      const char* pb = (const char*)P + (q << 9);
      int sw = (q & 7) << 4;
#pragma unroll
      for (int c = 0; c < 2; c++)
        pf[c] = *reinterpret_cast<const bf16x8*>(pb + (((kt << 7) + (c << 6) + (lhi << 4)) ^ sw));
    }
#pragma unroll
    for (int mf = 0; mf < 16; mf++) {
      int dl = (mf << 4) + llo;
      const char* vb = (const char*)KV + (dl << 7);
      int sw = (dl & 7) << 4;
#pragma unroll
      for (int c = 0; c < 2; c++) {
        bf16x8 vf = *reinterpret_cast<const bf16x8*>(vb + (((lhi << 4) + (c << 6)) ^ sw));
        cacc[mf] = MFMA16(vf, pf[c], cacc[mf]);
      }
    }
  }
  int token = (b << 8) + (qt << 6) + (wid << 4) + llo;
  u16* crow = ctx + (size_t)token * 4096 + (h << 8);
#pragma unroll
  for (int mf = 0; mf < 16; mf++) {
    ushort4 u;
    u.x = f2bf(cacc[mf][0]); u.y = f2bf(cacc[mf][1]);
    u.z = f2bf(cacc[mf][2]); u.w = f2bf(cacc[mf][3]);
    *reinterpret_cast<ushort4*>(crow + (mf << 4) + (lhi << 2)) = u;
  }
}

extern "C" void kernel_launch(void* const* d_in, const int* in_sizes, int n_in,
                              void* d_out, int out_size, void* d_ws, size_t ws_size,
                              hipStream_t stream) {
  const float* inp  = (const float*)d_in[0];
  const int*   mask = (const int*)d_in[1];
  const float* w    = (const float*)d_in[2];
  const float* bia  = (const float*)d_in[3];
  const float* qkvw = (const float*)d_in[4];
  const float* ow   = (const float*)d_in[5];
  const size_t MB = 1024ull * 1024ull;
  if (ws_size < 352 * MB) return;  // ws layout below needs 352 MiB
  char* ws = (char*)d_ws;
  u16* xn   = (u16*)(ws);             // 64 MiB  [0,64)
  u16* qkvT = (u16*)(ws + 64 * MB);   // 96 MiB  [64,160)
  u16* qk   = (u16*)(ws + 160 * MB);  // 128 MiB [160,288): [8192 tok][8192]
  u16* vT   = (u16*)(ws + 288 * MB);  // 64 MiB  [288,352): [b][h][d][s]
  u16* oT   = (u16*)(ws + 64 * MB);   // overlays qkvT (dead after QKV GEMM)
  u16* ctx  = (u16*)(ws);             // overlays xn (dead after QKV GEMM)
  float* out = (float*)d_out;

  transpose_bf16<<<49152, 256, 0, stream>>>(qkvw, qkvT, 4096, 12288);
  ln_bf16<<<8192, 256, 0, stream>>>(inp, w, bia, xn);
  gemm256<1><<<1536, 512, 0, stream>>>(xn, qkvT, (void*)qk, vT, 8192, 12288, 4096, 48);
  transpose_bf16<<<16384, 256, 0, stream>>>(ow, oT, 4096, 4096);
  attn_kernel<<<2048, 256, 0, stream>>>(qk, vT, mask, ctx);
  gemm256<2><<<512, 512, 0, stream>>>(ctx, oT, (void*)out, nullptr, 8192, 4096, 4096, 16);
}